// Round 2
// baseline (299.220 us; speedup 1.0000x reference)
//
#include <hip/hip_runtime.h>
#include <hip/hip_bf16.h>
#include <stdint.h>

// ViewLoRALinear: out[25088,1024] = x@W^T + b + (x@A_v)@B_v, all fp32 in/out.
// No fp32 MFMA on CDNA4 -> convert x,W to bf16 (RNE) in d_ws, run m97-structure
// bf16 MFMA GEMM with fp32 accum; LoRA h precomputed in fp32 (rank 4, exact).
#define M_TOT 25088
#define N_TOT 1024
#define K_TOT 1024
#define T_LEN 196
#define NVIEW 11

#define BM 128
#define BN 128
#define BK 64

typedef unsigned short u16;
typedef __bf16 bf16x8 __attribute__((ext_vector_type(8)));
typedef float f32x4 __attribute__((ext_vector_type(4)));
typedef unsigned short u16x4 __attribute__((ext_vector_type(4)));

// ws layout (fast path): [x_bf16: 25088*1024 u16][W_bf16: 1024*1024 u16][h: 25088*4 f32]
#define XB_ELEMS (M_TOT * (size_t)K_TOT)
#define WB_ELEMS (N_TOT * (size_t)K_TOT)
#define WB_OFF_B (XB_ELEMS * 2)                       // 51,380,224
#define H_OFF_B  (WB_OFF_B + WB_ELEMS * 2)            // 53,477,376
#define WS_NEEDED (H_OFF_B + (size_t)M_TOT * 4 * 4)   // 53,878,784

__device__ __forceinline__ u16 f2bf(float f) {
    union { float f; unsigned int i; } c; c.f = f;
    unsigned int i = c.i;
    return (u16)((i + 0x7FFFu + ((i >> 16) & 1u)) >> 16);  // RNE (inputs finite)
}

// ---------------------------------------------------------------------------
// Kernel 1 (fast path): convert x,W fp32->bf16 into ws, and compute
// h[row,0..3] = sum_k x[row,k]*A_v[k,r] in fp32. One wave per row.
// Blocks 0..6271: x rows (4/block) + h.  Blocks 6272..6527: W rows (4/block).
// ---------------------------------------------------------------------------
__global__ __launch_bounds__(256) void convert_h_kernel(
    const float* __restrict__ x, const float* __restrict__ W,
    const int* __restrict__ view_idx, const float* __restrict__ lora_A,
    u16* __restrict__ xb, u16* __restrict__ wb, float* __restrict__ h) {
    const int wave = threadIdx.x >> 6;
    const int lane = threadIdx.x & 63;
    const int blk  = blockIdx.x;

    if (blk >= M_TOT / 4) {  // W conversion
        const int row = (blk - M_TOT / 4) * 4 + wave;
        const float* src = W + (size_t)row * K_TOT;
        u16* dst = wb + (size_t)row * K_TOT;
#pragma unroll
        for (int it = 0; it < 4; ++it) {
            const int k = it * 256 + lane * 4;
            float4 v = *(const float4*)(src + k);
            u16x4 o = { f2bf(v.x), f2bf(v.y), f2bf(v.z), f2bf(v.w) };
            *(u16x4*)(dst + k) = o;
        }
        return;
    }

    const int row = blk * 4 + wave;
    const int bf  = row / T_LEN;
    int v = view_idx[bf >> 3];  // 8 frames per view entry (BF=128, B=16)
    v = v < 0 ? 0 : (v > NVIEW - 1 ? NVIEW - 1 : v);
    const float* A  = lora_A + (size_t)v * (K_TOT * 4);
    const float* xr = x + (size_t)row * K_TOT;
    u16* dst = xb + (size_t)row * K_TOT;

    float a0 = 0.f, a1 = 0.f, a2 = 0.f, a3 = 0.f;
#pragma unroll
    for (int it = 0; it < 4; ++it) {
        const int k = it * 256 + lane * 4;
        float4 xv = *(const float4*)(xr + k);
        u16x4 o = { f2bf(xv.x), f2bf(xv.y), f2bf(xv.z), f2bf(xv.w) };
        *(u16x4*)(dst + k) = o;
        const float xf[4] = { xv.x, xv.y, xv.z, xv.w };
#pragma unroll
        for (int j = 0; j < 4; ++j) {
            float4 av = *(const float4*)(A + (size_t)(k + j) * 4);
            a0 += xf[j] * av.x; a1 += xf[j] * av.y;
            a2 += xf[j] * av.z; a3 += xf[j] * av.w;
        }
    }
#pragma unroll
    for (int off = 32; off > 0; off >>= 1) {
        a0 += __shfl_xor(a0, off, 64);
        a1 += __shfl_xor(a1, off, 64);
        a2 += __shfl_xor(a2, off, 64);
        a3 += __shfl_xor(a3, off, 64);
    }
    if (lane == 0)
        *(float4*)(h + (size_t)row * 4) = make_float4(a0, a1, a2, a3);
}

// Fallback h-only kernel (when ws too small for conversion buffers).
__global__ __launch_bounds__(256) void h_only_kernel(
    const float* __restrict__ x, const int* __restrict__ view_idx,
    const float* __restrict__ lora_A, float* __restrict__ h) {
    const int row  = blockIdx.x * 4 + (threadIdx.x >> 6);
    const int lane = threadIdx.x & 63;
    int v = view_idx[(row / T_LEN) >> 3];
    v = v < 0 ? 0 : (v > NVIEW - 1 ? NVIEW - 1 : v);
    const float* A  = lora_A + (size_t)v * (K_TOT * 4);
    const float* xr = x + (size_t)row * K_TOT;
    float a0 = 0.f, a1 = 0.f, a2 = 0.f, a3 = 0.f;
#pragma unroll
    for (int it = 0; it < 4; ++it) {
        const int k = it * 256 + lane * 4;
        float4 xv = *(const float4*)(xr + k);
        const float xf[4] = { xv.x, xv.y, xv.z, xv.w };
#pragma unroll
        for (int j = 0; j < 4; ++j) {
            float4 av = *(const float4*)(A + (size_t)(k + j) * 4);
            a0 += xf[j] * av.x; a1 += xf[j] * av.y;
            a2 += xf[j] * av.z; a3 += xf[j] * av.w;
        }
    }
#pragma unroll
    for (int off = 32; off > 0; off >>= 1) {
        a0 += __shfl_xor(a0, off, 64);
        a1 += __shfl_xor(a1, off, 64);
        a2 += __shfl_xor(a2, off, 64);
        a3 += __shfl_xor(a3, off, 64);
    }
    if (lane == 0)
        *(float4*)(h + (size_t)row * 4) = make_float4(a0, a1, a2, a3);
}

// ---------------------------------------------------------------------------
// Kernel 2: m97-structure GEMM C = X*W^T + bias + h*B_v, fp32 out.
// CONV=false: bf16 tiles in ws, global_load_lds width-16 staging.
// CONV=true : fp32 tiles in global, VGPR load + cvt + ds_write staging.
// ---------------------------------------------------------------------------
template <bool CONV>
__global__ __launch_bounds__(256) void gemm_lora_kernel(
    const void* __restrict__ xp, const void* __restrict__ Wp,
    const float* __restrict__ bias, const int* __restrict__ view_idx,
    const float* __restrict__ lora_B, const float* __restrict__ h,
    float* __restrict__ out) {
    __shared__ u16 As[BM * BK];   // 16 KB [BM][BK] bf16
    __shared__ u16 Bs[BN * BK];   // 16 KB [BN][BK] bf16

    const int tid  = threadIdx.x;
    const int bx   = blockIdx.x;   // N tile 0..7
    const int by   = blockIdx.y;   // M tile 0..195
    const int lane = tid & 63;
    const int wave = tid >> 6;
    const int wm   = (wave >> 1) * 64;
    const int wn   = (wave & 1) * 64;
    const int l16  = lane & 15;
    const int quad = lane >> 4;

    const size_t a_base = (size_t)(by * BM) * K_TOT;
    const size_t b_base = (size_t)(bx * BN) * K_TOT;

    f32x4 acc[4][4] = {};

    for (int kt = 0; kt < K_TOT / BK; ++kt) {
        const int kofs = kt * BK;
        if constexpr (!CONV) {
            const u16* x = (const u16*)xp;
            const u16* W = (const u16*)Wp;
#pragma unroll
            for (int i = 0; i < 4; ++i) {
                const int e = i * 2048 + tid * 8;     // elem idx; LDS byte = 2e = wave-base + lane*16
                const int r = e >> 6, c = e & 63;
                __builtin_amdgcn_global_load_lds(
                    (const __attribute__((address_space(1))) void*)(x + a_base + (size_t)r * K_TOT + kofs + c),
                    (__attribute__((address_space(3))) void*)(As + e), 16, 0, 0);
                __builtin_amdgcn_global_load_lds(
                    (const __attribute__((address_space(1))) void*)(W + b_base + (size_t)r * K_TOT + kofs + c),
                    (__attribute__((address_space(3))) void*)(Bs + e), 16, 0, 0);
            }
        } else {
            const float* x = (const float*)xp;
            const float* W = (const float*)Wp;
#pragma unroll
            for (int i = 0; i < 8; ++i) {
                const int e = i * 1024 + tid * 4;
                const int r = e >> 6, c = e & 63;
                float4 av = *(const float4*)(x + a_base + (size_t)r * K_TOT + kofs + c);
                float4 bv = *(const float4*)(W + b_base + (size_t)r * K_TOT + kofs + c);
                u16x4 ao = { f2bf(av.x), f2bf(av.y), f2bf(av.z), f2bf(av.w) };
                u16x4 bo = { f2bf(bv.x), f2bf(bv.y), f2bf(bv.z), f2bf(bv.w) };
                *(u16x4*)(As + e) = ao;
                *(u16x4*)(Bs + e) = bo;
            }
        }
        __syncthreads();
#pragma unroll
        for (int kk = 0; kk < 2; ++kk) {
            const int k0 = kk * 32 + quad * 8;
            bf16x8 a_frag[4], b_frag[4];
#pragma unroll
            for (int mi = 0; mi < 4; ++mi)
                a_frag[mi] = *(const bf16x8*)(const void*)(As + (wm + mi * 16 + l16) * BK + k0);
#pragma unroll
            for (int ni = 0; ni < 4; ++ni)
                b_frag[ni] = *(const bf16x8*)(const void*)(Bs + (wn + ni * 16 + l16) * BK + k0);
#pragma unroll
            for (int mi = 0; mi < 4; ++mi)
#pragma unroll
                for (int ni = 0; ni < 4; ++ni)
                    acc[mi][ni] = __builtin_amdgcn_mfma_f32_16x16x32_bf16(
                        a_frag[mi], b_frag[ni], acc[mi][ni], 0, 0, 0);
        }
        __syncthreads();
    }

    // Epilogue: out = acc + bias + sum_r h[row,r]*B_v[r,col].
    // C/D layout (m89): col = lane&15, row = quad*4 + reg.
    const int rowBase = by * BM + wm;
    const int colBase = bx * BN + wn;
    float biasv[4];
#pragma unroll
    for (int ni = 0; ni < 4; ++ni) biasv[ni] = bias[colBase + ni * 16 + l16];

#pragma unroll
    for (int mi = 0; mi < 4; ++mi) {
#pragma unroll
        for (int reg = 0; reg < 4; ++reg) {
            const int grow = rowBase + mi * 16 + quad * 4 + reg;
            int v = view_idx[(grow / T_LEN) >> 3];
            v = v < 0 ? 0 : (v > NVIEW - 1 ? NVIEW - 1 : v);
            const float4 hv = *(const float4*)(h + (size_t)grow * 4);
            const float* Bv = lora_B + (size_t)v * (4 * N_TOT);
            float* orow = out + (size_t)grow * N_TOT;
#pragma unroll
            for (int ni = 0; ni < 4; ++ni) {
                const int gcol = colBase + ni * 16 + l16;
                float lora = hv.x * Bv[gcol]
                           + hv.y * Bv[N_TOT + gcol]
                           + hv.z * Bv[2 * N_TOT + gcol]
                           + hv.w * Bv[3 * N_TOT + gcol];
                orow[gcol] = acc[mi][ni][reg] + biasv[ni] + lora;
            }
        }
    }
}

extern "C" void kernel_launch(void* const* d_in, const int* in_sizes, int n_in,
                              void* d_out, int out_size, void* d_ws, size_t ws_size,
                              hipStream_t stream) {
    const float* x        = (const float*)d_in[0];
    const int*   view_idx = (const int*)d_in[1];
    const float* W        = (const float*)d_in[2];
    const float* b        = (const float*)d_in[3];
    const float* lora_A   = (const float*)d_in[4];
    const float* lora_B   = (const float*)d_in[5];
    float* out = (float*)d_out;

    const dim3 ggrid(N_TOT / BN, M_TOT / BM);
    if (ws_size >= WS_NEEDED) {
        u16*   xb = (u16*)d_ws;
        u16*   wb = (u16*)((char*)d_ws + WB_OFF_B);
        float* h  = (float*)((char*)d_ws + H_OFF_B);
        hipLaunchKernelGGL(convert_h_kernel, dim3(M_TOT / 4 + N_TOT / 4), dim3(256), 0, stream,
                           x, W, view_idx, lora_A, xb, wb, h);
        hipLaunchKernelGGL((gemm_lora_kernel<false>), ggrid, dim3(256), 0, stream,
                           xb, wb, b, view_idx, lora_B, h, out);
    } else {
        float* h = (float*)d_ws;  // 401,408 B
        hipLaunchKernelGGL(h_only_kernel, dim3(M_TOT / 4), dim3(256), 0, stream,
                           x, view_idx, lora_A, h);
        hipLaunchKernelGGL((gemm_lora_kernel<true>), ggrid, dim3(256), 0, stream,
                           x, W, b, view_idx, lora_B, h, out);
    }
}